// Round 4
// baseline (1234.551 us; speedup 1.0000x reference)
//
#include <hip/hip_runtime.h>
#include <stdint.h>

// Instant-NGP HashGrid forward, MI355X. Gather-bound (TA/TCP lines).
// R3: 128-thr blocks + 16KB LDS tile -> 10 blocks/CU = 20 waves/CU (the
// LDS-staging occupancy max); float4-granularity swizzled tile (b64 writes,
// b128 reads, float4 coalesced stores); nontemporal loads on hashed gathers.

#define NLVL 16
#define TS 65536
#define P2 2654435761u
#define P3 805459861u

typedef float v4f __attribute__((ext_vector_type(4)));
typedef float v2f __attribute__((ext_vector_type(2)));

__constant__ float C_SCALES[NLVL] = {
    15.0f, 23.0f, 35.0f, 53.0f, 80.0f, 120.5f, 181.25f, 272.375f,
    409.0625f, 614.09375f, 921.640625f, 1382.9609375f,
    2074.94140625f, 3112.912109375f, 4669.8681640625f, 7005.30224609375f};

__device__ __forceinline__ v2f v4lo(v4f v) { v2f r; r.x = v.x; r.y = v.y; return r; }
__device__ __forceinline__ v2f v4hi(v4f v) { v2f r; r.x = v.z; r.y = v.w; return r; }

// Tile: [128 points][8 float4-groups], slot(p,g) = (g+p)&7.
// Level l -> group g=l>>1, half h=l&1 (two floats within the float4 slot).
__device__ __forceinline__ void lds_put2(float* s_out, int p, int l,
                                         float a, float b) {
    const int slot = ((l >> 1) + p) & 7;
    const int a32 = p * 32 + slot * 4 + (l & 1) * 2;  // 8B-aligned
    s_out[a32] = a;
    s_out[a32 + 1] = b;
}

__global__ __launch_bounds__(128, 5) void hashgrid_fwd(
    const float* __restrict__ x,
    const float* __restrict__ table,
    float* __restrict__ out,
    int n)
{
    __shared__ float s_out[128 * 32];  // 16 KiB swizzled transpose tile

    const int tid0 = blockIdx.x * 128 + threadIdx.x;
    const int tid = min(tid0, n - 1);
    const int p = threadIdx.x;

    const float px = x[3 * tid + 0];
    const float py = x[3 * tid + 1];
    const float pz = x[3 * tid + 2];

    // ---- dense levels 0..2 (small tables, keep in L1/L2), unrolled ----
    {
        const int RESO[3] = {16, 24, 36};
        const float DSC[3] = {15.0f, 23.0f, 35.0f};
#pragma unroll
        for (int l = 0; l < 3; ++l) {
            const float scale = DSC[l];
            const float fx = px * scale + 0.5f;
            const float fy = py * scale + 0.5f;
            const float fz = pz * scale + 0.5f;
            const float gx = floorf(fx), gy = floorf(fy), gz = floorf(fz);
            const float wx = fx - gx, wy = fy - gy, wz = fz - gz;
            const int ix = (int)gx, iy = (int)gy, iz = (int)gz;

            const v2f* tbl = ((const v2f*)table) + (size_t)l * TS;
            const int R = RESO[l];
            const int x0 = min(ix, R - 1);
            const int y0 = min(iy, R - 1), y1 = min(iy + 1, R - 1);
            const int z0 = min(iz, R - 1), z1 = min(iz + 1, R - 1);
            const int xb = min(x0, R - 2);
            const bool hi0 = (x0 != xb);
            const int y0R = y0 * R, y1R = y1 * R;
            const int z0R = z0 * R * R, z1R = z1 * R * R;
            const v4f f00 = *(const v4f*)(tbl + (xb + y0R + z0R));
            const v4f f01 = *(const v4f*)(tbl + (xb + y0R + z1R));
            const v4f f10 = *(const v4f*)(tbl + (xb + y1R + z0R));
            const v4f f11 = *(const v4f*)(tbl + (xb + y1R + z1R));
            const v2f c0 = hi0 ? v4hi(f00) : v4lo(f00), c4 = v4hi(f00);
            const v2f c1 = hi0 ? v4hi(f01) : v4lo(f01), c5 = v4hi(f01);
            const v2f c2 = hi0 ? v4hi(f10) : v4lo(f10), c6 = v4hi(f10);
            const v2f c3 = hi0 ? v4hi(f11) : v4lo(f11), c7 = v4hi(f11);

            const float ux = 1.0f - wx, uy = 1.0f - wy, uz = 1.0f - wz;
            const float w0 = ux * uy * uz, w1 = ux * uy * wz;
            const float w2 = ux * wy * uz, w3 = ux * wy * wz;
            const float w4 = wx * uy * uz, w5 = wx * uy * wz;
            const float w6 = wx * wy * uz, w7 = wx * wy * wz;

            const float o0 = w0 * c0.x + w1 * c1.x + w2 * c2.x + w3 * c3.x +
                             w4 * c4.x + w5 * c5.x + w6 * c6.x + w7 * c7.x;
            const float o1 = w0 * c0.y + w1 * c1.y + w2 * c2.y + w3 * c3.y +
                             w4 * c4.y + w5 * c5.y + w6 * c6.y + w7 * c7.y;
            lds_put2(s_out, p, l, o0, o1);
        }
    }

    // ---- hashed levels 3..15: rolled, unroll 2, nontemporal gathers ----
#pragma unroll 2
    for (int l = 3; l < NLVL; ++l) {
        const float scale = C_SCALES[l];
        const float fx = px * scale + 0.5f;
        const float fy = py * scale + 0.5f;
        const float fz = pz * scale + 0.5f;
        const float gx = floorf(fx), gy = floorf(fy), gz = floorf(fz);
        const float wx = fx - gx, wy = fy - gy, wz = fz - gz;
        const int ix = (int)gx, iy = (int)gy, iz = (int)gz;

        const v2f* tbl = ((const v2f*)table) + (size_t)l * TS;

        // h = x ^ y*P2 ^ z*P3 ; even x: h(x+1) = h(x)^1 (same aligned pair)
        const uint32_t bx = (uint32_t)ix;
        const uint32_t hy0 = (uint32_t)iy * P2, hy1 = hy0 + P2;
        const uint32_t hz0 = (uint32_t)iz * P3, hz1 = hz0 + P3;
        const uint32_t b00 = hy0 ^ hz0, b01 = hy0 ^ hz1;
        const uint32_t b10 = hy1 ^ hz0, b11 = hy1 ^ hz1;
        const uint32_t i00 = (bx ^ b00) & (TS - 1);
        const uint32_t i01 = (bx ^ b01) & (TS - 1);
        const uint32_t i10 = (bx ^ b10) & (TS - 1);
        const uint32_t i11 = (bx ^ b11) & (TS - 1);
        const v4f* tbl4 = (const v4f*)tbl;
        const v4f f00 = __builtin_nontemporal_load(tbl4 + (i00 >> 1));
        const v4f f01 = __builtin_nontemporal_load(tbl4 + (i01 >> 1));
        const v4f f10 = __builtin_nontemporal_load(tbl4 + (i10 >> 1));
        const v4f f11 = __builtin_nontemporal_load(tbl4 + (i11 >> 1));
        const v2f c0 = (i00 & 1) ? v4hi(f00) : v4lo(f00);
        const v2f c1 = (i01 & 1) ? v4hi(f01) : v4lo(f01);
        const v2f c2 = (i10 & 1) ? v4hi(f10) : v4lo(f10);
        const v2f c3 = (i11 & 1) ? v4hi(f10) : v4lo(f10);  // placeholder, fixed below
        v2f c3x = (i11 & 1) ? v4hi(f11) : v4lo(f11);
        v2f c4, c5, c6, c7;
        if ((ix & 1) == 0) {
            c4 = (i00 & 1) ? v4lo(f00) : v4hi(f00);
            c5 = (i01 & 1) ? v4lo(f01) : v4hi(f01);
            c6 = (i10 & 1) ? v4lo(f10) : v4hi(f10);
            c7 = (i11 & 1) ? v4lo(f11) : v4hi(f11);
        } else {
            const uint32_t bx1 = bx + 1;
            c4 = __builtin_nontemporal_load(tbl + ((bx1 ^ b00) & (TS - 1)));
            c5 = __builtin_nontemporal_load(tbl + ((bx1 ^ b01) & (TS - 1)));
            c6 = __builtin_nontemporal_load(tbl + ((bx1 ^ b10) & (TS - 1)));
            c7 = __builtin_nontemporal_load(tbl + ((bx1 ^ b11) & (TS - 1)));
        }

        const float ux = 1.0f - wx, uy = 1.0f - wy, uz = 1.0f - wz;
        const float w0 = ux * uy * uz, w1 = ux * uy * wz;
        const float w2 = ux * wy * uz, w3 = ux * wy * wz;
        const float w4 = wx * uy * uz, w5 = wx * uy * wz;
        const float w6 = wx * wy * uz, w7 = wx * wy * wz;

        const float o0 = w0 * c0.x + w1 * c1.x + w2 * c2.x + w3 * c3x.x +
                         w4 * c4.x + w5 * c5.x + w6 * c6.x + w7 * c7.x;
        const float o1 = w0 * c0.y + w1 * c1.y + w2 * c2.y + w3 * c3x.y +
                         w4 * c4.y + w5 * c5.y + w6 * c6.y + w7 * c7.y;
        (void)c3;
        lds_put2(s_out, p, l, o0, o1);
    }

    __syncthreads();

    // ---- coalesced float4 stores: e = pt*8 + group ----
    v4f* outb4 = (v4f*)(out + (size_t)blockIdx.x * (128 * 32));
    const long long lim4 =
        ((long long)n * 8) - (long long)blockIdx.x * (128 * 8);
#pragma unroll
    for (int r = 0; r < 8; ++r) {
        const int e = r * 128 + threadIdx.x;  // 0..1023
        const int pp = e >> 3, g = e & 7;
        const int slot = (g + pp) & 7;
        const v4f v = *(const v4f*)&s_out[pp * 32 + slot * 4];
        if (e < lim4) outb4[e] = v;
    }
}

extern "C" void kernel_launch(void* const* d_in, const int* in_sizes, int n_in,
                              void* d_out, int out_size, void* d_ws, size_t ws_size,
                              hipStream_t stream) {
    const float* x = (const float*)d_in[0];     // [N,3] f32
    const float* table = (const float*)d_in[1]; // [16,65536,2] f32
    float* out = (float*)d_out;                 // [N,32] f32
    const int n = in_sizes[0] / 3;
    const int block = 128;
    const int grid = (n + block - 1) / block;
    hashgrid_fwd<<<grid, block, 0, stream>>>(x, table, out, n);
}

// Round 5
// 500.106 us; speedup vs baseline: 2.4686x; 2.4686x over previous
//
#include <hip/hip_runtime.h>
#include <stdint.h>

// Instant-NGP HashGrid forward, MI355X. Gather-bound.
// R4: revert nontemporal (R3: nt bypassed L2 -> FETCH 440MB->2.5GB, 2.3x dur).
// Occupancy test: two level-group halves (0..7, 8..15) through a 16KB
// [256pt x 16f] swizzled LDS tile -> 8 blocks/CU, 32 waves/CU (100%).
// Each half stores full 64B lines: out[p*32 + grp*16 .. +15].

#define NLVL 16
#define TS 65536
#define P2 2654435761u
#define P3 805459861u

typedef float v4f __attribute__((ext_vector_type(4)));
typedef float v2f __attribute__((ext_vector_type(2)));

__constant__ float C_SCALES[NLVL] = {
    15.0f, 23.0f, 35.0f, 53.0f, 80.0f, 120.5f, 181.25f, 272.375f,
    409.0625f, 614.09375f, 921.640625f, 1382.9609375f,
    2074.94140625f, 3112.912109375f, 4669.8681640625f, 7005.30224609375f};

__device__ __forceinline__ v2f v4lo(v4f v) { v2f r; r.x = v.x; r.y = v.y; return r; }
__device__ __forceinline__ v2f v4hi(v4f v) { v2f r; r.x = v.z; r.y = v.w; return r; }

// Half-tile: [256 pts][4 float4 slots]; level l (within half) -> group
// gl=(l>>1)-4*grp, half-bit h=l&1; slot(p,gl) = (gl+p)&3.
__device__ __forceinline__ void lds_put2(float* s, int p, int gl, int h,
                                         float a, float b) {
    const int slot = (gl + p) & 3;
    const int a32 = p * 16 + slot * 4 + h * 2;  // 8B-aligned
    s[a32] = a;
    s[a32 + 1] = b;
}

// One hashed level: returns interpolated (f0,f1).
__device__ __forceinline__ v2f hashed_level(float px, float py, float pz,
                                            float scale, const v2f* tbl) {
    const float fx = px * scale + 0.5f;
    const float fy = py * scale + 0.5f;
    const float fz = pz * scale + 0.5f;
    const float gx = floorf(fx), gy = floorf(fy), gz = floorf(fz);
    const float wx = fx - gx, wy = fy - gy, wz = fz - gz;
    const int ix = (int)gx, iy = (int)gy, iz = (int)gz;

    // h = x ^ y*P2 ^ z*P3 ; even x: h(x+1)=h(x)^1 -> same aligned float4 pair
    const uint32_t bx = (uint32_t)ix;
    const uint32_t hy0 = (uint32_t)iy * P2, hy1 = hy0 + P2;
    const uint32_t hz0 = (uint32_t)iz * P3, hz1 = hz0 + P3;
    const uint32_t b00 = hy0 ^ hz0, b01 = hy0 ^ hz1;
    const uint32_t b10 = hy1 ^ hz0, b11 = hy1 ^ hz1;
    const uint32_t i00 = (bx ^ b00) & (TS - 1);
    const uint32_t i01 = (bx ^ b01) & (TS - 1);
    const uint32_t i10 = (bx ^ b10) & (TS - 1);
    const uint32_t i11 = (bx ^ b11) & (TS - 1);
    const v4f* tbl4 = (const v4f*)tbl;
    const v4f f00 = tbl4[i00 >> 1];
    const v4f f01 = tbl4[i01 >> 1];
    const v4f f10 = tbl4[i10 >> 1];
    const v4f f11 = tbl4[i11 >> 1];
    const v2f c0 = (i00 & 1) ? v4hi(f00) : v4lo(f00);
    const v2f c1 = (i01 & 1) ? v4hi(f01) : v4lo(f01);
    const v2f c2 = (i10 & 1) ? v4hi(f10) : v4lo(f10);
    const v2f c3 = (i11 & 1) ? v4hi(f11) : v4lo(f11);
    v2f c4, c5, c6, c7;
    if ((ix & 1) == 0) {
        c4 = (i00 & 1) ? v4lo(f00) : v4hi(f00);
        c5 = (i01 & 1) ? v4lo(f01) : v4hi(f01);
        c6 = (i10 & 1) ? v4lo(f10) : v4hi(f10);
        c7 = (i11 & 1) ? v4lo(f11) : v4hi(f11);
    } else {
        const uint32_t bx1 = bx + 1;
        c4 = tbl[(bx1 ^ b00) & (TS - 1)];
        c5 = tbl[(bx1 ^ b01) & (TS - 1)];
        c6 = tbl[(bx1 ^ b10) & (TS - 1)];
        c7 = tbl[(bx1 ^ b11) & (TS - 1)];
    }

    const float ux = 1.0f - wx, uy = 1.0f - wy, uz = 1.0f - wz;
    const float w0 = ux * uy * uz, w1 = ux * uy * wz;
    const float w2 = ux * wy * uz, w3 = ux * wy * wz;
    const float w4 = wx * uy * uz, w5 = wx * uy * wz;
    const float w6 = wx * wy * uz, w7 = wx * wy * wz;

    v2f o;
    o.x = w0 * c0.x + w1 * c1.x + w2 * c2.x + w3 * c3.x +
          w4 * c4.x + w5 * c5.x + w6 * c6.x + w7 * c7.x;
    o.y = w0 * c0.y + w1 * c1.y + w2 * c2.y + w3 * c3.y +
          w4 * c4.y + w5 * c5.y + w6 * c6.y + w7 * c7.y;
    return o;
}

__global__ __launch_bounds__(256, 8) void hashgrid_fwd(
    const float* __restrict__ x,
    const float* __restrict__ table,
    float* __restrict__ out,
    int n)
{
    __shared__ float s_out[256 * 16];  // 16 KiB half-tile

    const int tid0 = blockIdx.x * 256 + threadIdx.x;
    const int tid = min(tid0, n - 1);
    const int p = threadIdx.x;

    const float px = x[3 * tid + 0];
    const float py = x[3 * tid + 1];
    const float pz = x[3 * tid + 2];

    v4f* outb4 = (v4f*)out + (size_t)blockIdx.x * (256 * 8);
    const long long lim4 = (long long)n * 8 - (long long)blockIdx.x * (256 * 8);

    // ================= half 0: levels 0..7 =================
    // dense levels 0..2 (small tables, L1/L2-hot), unrolled
    {
        const int RESO[3] = {16, 24, 36};
        const float DSC[3] = {15.0f, 23.0f, 35.0f};
#pragma unroll
        for (int l = 0; l < 3; ++l) {
            const float scale = DSC[l];
            const float fx = px * scale + 0.5f;
            const float fy = py * scale + 0.5f;
            const float fz = pz * scale + 0.5f;
            const float gx = floorf(fx), gy = floorf(fy), gz = floorf(fz);
            const float wx = fx - gx, wy = fy - gy, wz = fz - gz;
            const int ix = (int)gx, iy = (int)gy, iz = (int)gz;

            const v2f* tbl = ((const v2f*)table) + (size_t)l * TS;
            const int R = RESO[l];
            const int x0 = min(ix, R - 1);
            const int y0 = min(iy, R - 1), y1 = min(iy + 1, R - 1);
            const int z0 = min(iz, R - 1), z1 = min(iz + 1, R - 1);
            const int xb = min(x0, R - 2);
            const bool hi0 = (x0 != xb);
            const int y0R = y0 * R, y1R = y1 * R;
            const int z0R = z0 * R * R, z1R = z1 * R * R;
            const v4f f00 = *(const v4f*)(tbl + (xb + y0R + z0R));
            const v4f f01 = *(const v4f*)(tbl + (xb + y0R + z1R));
            const v4f f10 = *(const v4f*)(tbl + (xb + y1R + z0R));
            const v4f f11 = *(const v4f*)(tbl + (xb + y1R + z1R));
            const v2f c0 = hi0 ? v4hi(f00) : v4lo(f00), c4 = v4hi(f00);
            const v2f c1 = hi0 ? v4hi(f01) : v4lo(f01), c5 = v4hi(f01);
            const v2f c2 = hi0 ? v4hi(f10) : v4lo(f10), c6 = v4hi(f10);
            const v2f c3 = hi0 ? v4hi(f11) : v4lo(f11), c7 = v4hi(f11);

            const float ux = 1.0f - wx, uy = 1.0f - wy, uz = 1.0f - wz;
            const float w0 = ux * uy * uz, w1 = ux * uy * wz;
            const float w2 = ux * wy * uz, w3 = ux * wy * wz;
            const float w4 = wx * uy * uz, w5 = wx * uy * wz;
            const float w6 = wx * wy * uz, w7 = wx * wy * wz;

            const float o0 = w0 * c0.x + w1 * c1.x + w2 * c2.x + w3 * c3.x +
                             w4 * c4.x + w5 * c5.x + w6 * c6.x + w7 * c7.x;
            const float o1 = w0 * c0.y + w1 * c1.y + w2 * c2.y + w3 * c3.y +
                             w4 * c4.y + w5 * c5.y + w6 * c6.y + w7 * c7.y;
            lds_put2(s_out, p, l >> 1, l & 1, o0, o1);
        }
    }
    // hashed levels 3..7
#pragma unroll 2
    for (int l = 3; l < 8; ++l) {
        const v2f o = hashed_level(px, py, pz, C_SCALES[l],
                                   ((const v2f*)table) + (size_t)l * TS);
        lds_put2(s_out, p, l >> 1, l & 1, o.x, o.y);
    }
    __syncthreads();
    // store half 0: features 0..15 of each point = full 64B lines
#pragma unroll
    for (int r = 0; r < 4; ++r) {
        const int e = r * 256 + threadIdx.x;   // 0..1023
        const int pp = e >> 2, g = e & 3;
        const int slot = (g + pp) & 3;
        const v4f v = *(const v4f*)&s_out[pp * 16 + slot * 4];
        const int o4 = pp * 8 + g;             // first half of point pp
        if (o4 < lim4) outb4[o4] = v;
    }
    __syncthreads();

    // ================= half 1: levels 8..15 =================
#pragma unroll 2
    for (int l = 8; l < NLVL; ++l) {
        const v2f o = hashed_level(px, py, pz, C_SCALES[l],
                                   ((const v2f*)table) + (size_t)l * TS);
        lds_put2(s_out, p, (l >> 1) - 4, l & 1, o.x, o.y);
    }
    __syncthreads();
    // store half 1: features 16..31
#pragma unroll
    for (int r = 0; r < 4; ++r) {
        const int e = r * 256 + threadIdx.x;
        const int pp = e >> 2, g = e & 3;
        const int slot = (g + pp) & 3;
        const v4f v = *(const v4f*)&s_out[pp * 16 + slot * 4];
        const int o4 = pp * 8 + 4 + g;         // second half of point pp
        if (o4 < lim4) outb4[o4] = v;
    }
}

extern "C" void kernel_launch(void* const* d_in, const int* in_sizes, int n_in,
                              void* d_out, int out_size, void* d_ws, size_t ws_size,
                              hipStream_t stream) {
    const float* x = (const float*)d_in[0];     // [N,3] f32
    const float* table = (const float*)d_in[1]; // [16,65536,2] f32
    float* out = (float*)d_out;                 // [N,32] f32
    const int n = in_sizes[0] / 3;
    const int block = 256;
    const int grid = (n + block - 1) / block;
    hashgrid_fwd<<<grid, block, 0, stream>>>(x, table, out, n);
}